// Round 8
// baseline (165.073 us; speedup 1.0000x reference)
//
#include <hip/hip_runtime.h>
#include <math.h>

#define BB 4
#define HH 64
#define WW 64
#define CC 256
#define NN 4096   // H*W
#define MM 1024   // (H/2)*(W/2)
#define LN_EPS 1e-6f
#define SLF (0.17677669529663687f * 1.4426950408889634f)

typedef __attribute__((ext_vector_type(8)))  short short8;
typedef __attribute__((ext_vector_type(16))) float f32x16;
typedef __attribute__((ext_vector_type(4)))  unsigned int uint32x4;

__device__ __forceinline__ ushort f2bf(float f) {
  unsigned u = __builtin_bit_cast(unsigned, f);
  u += 0x7fffu + ((u >> 16) & 1u);   // RNE
  return (ushort)(u >> 16);
}
__device__ __forceinline__ float bf2f(ushort h) {
  unsigned u = ((unsigned)h) << 16;
  return __builtin_bit_cast(float, u);
}
#if __has_builtin(__builtin_amdgcn_exp2f)
#define EXP2F(x) __builtin_amdgcn_exp2f(x)
#else
#define EXP2F(x) exp2f(x)
#endif

// ---------------------------------------------------------------------------
// 1) FUSED front end — VECTORIZED (4 channels/lane, float4 loads; G13).
//    blocks [0,1024):      srln — ONE WAVE PER ROW, pure shfl reduction
//                          (no LDS, no barrier; was 1 block/row + barrier)
//    blocks [1024,1536):   dwconv 3x3 — 4ch/lane float4, 4x fewer mem insts
//    blocks [1536,1600):   pw_w  f32 -> bf16
//    blocks [1600,1728):   kv_w  f32 -> bf16
//    blocks [1728,1792):   proj_w f32 -> bf16 hi/lo split
__global__ __launch_bounds__(256) void pre_fused(
    const float* __restrict__ x, const float* __restrict__ dw_w,
    const float* __restrict__ dw_b, const float* __restrict__ sr_w,
    const float* __restrict__ ln_g, const float* __restrict__ ln_b,
    const float* __restrict__ pw_w, const float* __restrict__ kv_w,
    const float* __restrict__ proj_w,
    ushort* __restrict__ q1b, ushort* __restrict__ xsr,
    ushort* __restrict__ pwB, ushort* __restrict__ kvB,
    ushort* __restrict__ pjH, ushort* __restrict__ pjL) {
  int bid = blockIdx.x;
  int t = threadIdx.x;
  int wv = t >> 6, lane = t & 63;
  if (bid < 1024) {
    // srln: wave wv handles row g = bid*4+wv; lane handles channels 4l..4l+3
    int g = bid * 4 + wv;
    int b = g >> 10, m = g & 1023;
    int my = m >> 5, mx = m & 31;
    int c4 = lane * 4;
    float wl[36];
#pragma unroll
    for (int k = 0; k < 9; ++k)
      *(float4*)&wl[4 * k] = *(const float4*)&sr_w[c4 * 9 + 4 * k];
    const float* xb = x + (size_t)b * NN * CC + c4;
    float4 acc = {0.f, 0.f, 0.f, 0.f};
#pragma unroll
    for (int dy = 0; dy < 3; ++dy) {
      int iy = 2 * my + dy - 1;
      if (iy < 0 || iy >= HH) continue;
#pragma unroll
      for (int dx = 0; dx < 3; ++dx) {
        int ix = 2 * mx + dx - 1;
        if (ix < 0 || ix >= WW) continue;
        float4 xv = *(const float4*)&xb[(size_t)(iy * WW + ix) * CC];
        int tap = dy * 3 + dx;
        acc.x += xv.x * wl[0 + tap];
        acc.y += xv.y * wl[9 + tap];
        acc.z += xv.z * wl[18 + tap];
        acc.w += xv.w * wl[27 + tap];
      }
    }
    float v1 = (acc.x + acc.y) + (acc.z + acc.w);
    float v2 = (acc.x * acc.x + acc.y * acc.y) + (acc.z * acc.z + acc.w * acc.w);
#pragma unroll
    for (int s = 1; s < 64; s <<= 1) {
      v1 += __shfl_xor(v1, s);
      v2 += __shfl_xor(v2, s);
    }
    float mu = v1 * (1.f / 256.f);
    float var = v2 * (1.f / 256.f) - mu * mu;
    float rs = rsqrtf(var + LN_EPS);
    float4 g4 = *(const float4*)&ln_g[c4];
    float4 b4 = *(const float4*)&ln_b[c4];
    ushort o4[4];
    o4[0] = f2bf((acc.x - mu) * rs * g4.x + b4.x);
    o4[1] = f2bf((acc.y - mu) * rs * g4.y + b4.y);
    o4[2] = f2bf((acc.z - mu) * rs * g4.z + b4.z);
    o4[3] = f2bf((acc.w - mu) * rs * g4.w + b4.w);
    *(uint2*)&xsr[((size_t)b * MM + m) * CC + c4] = *(uint2*)o4;
  } else if (bid < 1536) {
    // dwconv: wave wv handles row-segment R = (bid-1024)*4+wv; 4ch/lane
    int R = (bid - 1024) * 4 + wv;       // 0..2047
    int b = R >> 9, r = R & 511;
    int y = r >> 3, seg = r & 7;
    int x0 = seg * 8;
    int c4 = lane * 4;
    float wl[36];
#pragma unroll
    for (int k = 0; k < 9; ++k)
      *(float4*)&wl[4 * k] = *(const float4*)&dw_w[c4 * 9 + 4 * k];
    float4 bi = *(const float4*)&dw_b[c4];
    const float* xb = x + (size_t)b * NN * CC + c4;
    bool okT = (y > 0), okB = (y < 63);
    const float4 z4 = {0.f, 0.f, 0.f, 0.f};
#define LD4(pt) (*(const float4*)&xb[(size_t)(pt) * CC])
    float4 a0, a1, a2, b0, b1, b2;
    if (x0 == 0) {
      a0 = a1 = a2 = z4;
    } else {
      a0 = okT ? LD4((y - 1) * 64 + x0 - 1) : z4;
      a1 = LD4(y * 64 + x0 - 1);
      a2 = okB ? LD4((y + 1) * 64 + x0 - 1) : z4;
    }
    b0 = okT ? LD4((y - 1) * 64 + x0) : z4;
    b1 = LD4(y * 64 + x0);
    b2 = okB ? LD4((y + 1) * 64 + x0) : z4;
    ushort* ob = q1b + ((size_t)b * NN + y * 64) * CC + c4;
#pragma unroll 8
    for (int xx = x0; xx < x0 + 8; ++xx) {
      float4 c0v, c1v, c2v;
      if (xx < 63) {
        c0v = okT ? LD4((y - 1) * 64 + xx + 1) : z4;
        c1v = LD4(y * 64 + xx + 1);
        c2v = okB ? LD4((y + 1) * 64 + xx + 1) : z4;
      } else {
        c0v = c1v = c2v = z4;
      }
      float4 acc = bi;
      acc.x += a0.x * wl[0] + b0.x * wl[1] + c0v.x * wl[2] +
               a1.x * wl[3] + b1.x * wl[4] + c1v.x * wl[5] +
               a2.x * wl[6] + b2.x * wl[7] + c2v.x * wl[8];
      acc.y += a0.y * wl[9] + b0.y * wl[10] + c0v.y * wl[11] +
               a1.y * wl[12] + b1.y * wl[13] + c1v.y * wl[14] +
               a2.y * wl[15] + b2.y * wl[16] + c2v.y * wl[17];
      acc.z += a0.z * wl[18] + b0.z * wl[19] + c0v.z * wl[20] +
               a1.z * wl[21] + b1.z * wl[22] + c1v.z * wl[23] +
               a2.z * wl[24] + b2.z * wl[25] + c2v.z * wl[26];
      acc.w += a0.w * wl[27] + b0.w * wl[28] + c0v.w * wl[29] +
               a1.w * wl[30] + b1.w * wl[31] + c1v.w * wl[32] +
               a2.w * wl[33] + b2.w * wl[34] + c2v.w * wl[35];
      ushort o4[4] = {f2bf(acc.x), f2bf(acc.y), f2bf(acc.z), f2bf(acc.w)};
      *(uint2*)&ob[(size_t)xx * CC] = *(uint2*)o4;
      a0 = b0; a1 = b1; a2 = b2;
      b0 = c0v; b1 = c1v; b2 = c2v;
    }
#undef LD4
  } else if (bid < 1600) {
    int i0 = (bid - 1536) * 1024 + t * 4;
    float4 v = *(const float4*)&pw_w[i0];
    ushort tmp[4] = {f2bf(v.x), f2bf(v.y), f2bf(v.z), f2bf(v.w)};
    *(uint2*)&pwB[i0] = *(uint2*)tmp;
  } else if (bid < 1728) {
    int i0 = (bid - 1600) * 1024 + t * 4;
    float4 v = *(const float4*)&kv_w[i0];
    ushort tmp[4] = {f2bf(v.x), f2bf(v.y), f2bf(v.z), f2bf(v.w)};
    *(uint2*)&kvB[i0] = *(uint2*)tmp;
  } else {
    int i0 = (bid - 1728) * 1024 + t * 4;
    float4 v = *(const float4*)&proj_w[i0];
    float vv[4] = {v.x, v.y, v.z, v.w};
    ushort th[4], tl[4];
#pragma unroll
    for (int j = 0; j < 4; ++j) {
      th[j] = f2bf(vv[j]);
      tl[j] = f2bf(vv[j] - bf2f(th[j]));
    }
    *(uint2*)&pjH[i0] = *(uint2*)th;
    *(uint2*)&pjL[i0] = *(uint2*)tl;
  }
}

// ---------------------------------------------------------------------------
// 2) FUSED q-GEMM + kv-GEMM. 64x64 tiles, double-buffered single-barrier,
//    depth-2 register pipeline. (unchanged)
__global__ __launch_bounds__(256) void gemm_qkv(
    const ushort* __restrict__ q1b, const ushort* __restrict__ xsr,
    const ushort* __restrict__ pwB, const float* __restrict__ pw_b,
    const ushort* __restrict__ kvB, const float* __restrict__ kv_b,
    ushort* __restrict__ qB, ushort* __restrict__ kB,
    ushort* __restrict__ vT) {
  __shared__ ushort smem[2][128 * 40];
  int bid = blockIdx.x;
  bool is0 = bid < 1024;
  const ushort* A;
  const ushort* W;
  const float* bias;
  int r0, c0;
  if (is0) {
    A = q1b; W = pwB; bias = pw_b;
    r0 = (bid >> 2) * 64; c0 = (bid & 3) * 64;
  } else {
    int sid = bid - 1024;
    A = xsr; W = kvB; bias = kv_b;
    r0 = (sid >> 3) * 64; c0 = (sid & 7) * 64;
  }
  const bool vmode = (!is0) && (c0 >= 256);

  int t = threadIdx.x;
  int lane = t & 63, w = t >> 6;
  int l31 = lane & 31, half = lane >> 5;
  int wr = w >> 1, wc = w & 1;
  int rowA = t >> 2, kq = (t & 3) * 8;

  f32x16 acc;
#pragma unroll
  for (int i = 0; i < 16; ++i) acc[i] = 0.f;

  short8 ra[2], rw[2];
  auto prefetch = [&](int kc, int s) {
    ra[s] = *(const short8*)&A[(size_t)(r0 + rowA) * 256 + kc + kq];
    rw[s] = *(const short8*)&W[(size_t)(c0 + rowA) * 256 + kc + kq];
  };
  auto store = [&](ushort* buf, int s) {
    *(short8*)&buf[rowA * 40 + kq] = ra[s];
    *(short8*)&buf[64 * 40 + rowA * 40 + kq] = rw[s];
  };

  prefetch(0, 0);
  store(smem[0], 0);
  prefetch(32, 1);
  __syncthreads();
#pragma unroll
  for (int i = 0; i < 8; ++i) {
    ushort* cur = smem[i & 1];
    ushort* nxt = smem[(i & 1) ^ 1];
    if (i < 7) store(nxt, (i + 1) & 1);
    if (i < 6) prefetch((i + 2) * 32, i & 1);
#pragma unroll
    for (int ks = 0; ks < 2; ++ks) {
      short8 af = *(const short8*)&cur[(wr * 32 + l31) * 40 + ks * 16 + half * 8];
      short8 wf = *(const short8*)&cur[64 * 40 + (wc * 32 + l31) * 40 + ks * 16 + half * 8];
      if (vmode)
        acc = __builtin_amdgcn_mfma_f32_32x32x16_bf16(wf, af, acc, 0, 0, 0);
      else
        acc = __builtin_amdgcn_mfma_f32_32x32x16_bf16(af, wf, acc, 0, 0, 0);
    }
    __syncthreads();
  }

#pragma unroll
  for (int i = 0; i < 16; ++i) {
    int rl = (i & 3) + 8 * (i >> 2) + 4 * half;
    if (is0) {
      int r = r0 + wr * 32 + rl;
      int c = c0 + wc * 32 + l31;
      int b = r >> 12, n = r & 4095;
      int h = c >> 5, d = c & 31;
      qB[((size_t)(b * 8 + h) * NN + n) * 32 + d] =
          f2bf((acc[i] + bias[c]) * SLF);
    } else if (!vmode) {
      int r = r0 + wr * 32 + rl;
      int c = c0 + wc * 32 + l31;
      int b = r >> 10, m = r & 1023;
      int h = c >> 5, d = c & 31;
      kB[((size_t)(b * 8 + h) * MM + m) * 32 + d] = f2bf(acc[i] + bias[c]);
    } else {
      int c = c0 + wc * 32 + rl;
      int r = r0 + wr * 32 + l31;
      int b = r >> 10, m = r & 1023;
      int cv = c - 256;
      int h = cv >> 5, d = cv & 31;
      vT[((size_t)(b * 8 + h) * 32 + d) * MM + m] = f2bf(acc[i] + bias[c]);
    }
  }
}

// ---------------------------------------------------------------------------
// 3) MFMA flash attention — NOW 256 Q-ROWS PER BLOCK (2 sets of 128,
//    processed sequentially per chunk to cap register pressure). Halves
//    K/V global staging, LDS stores, and barriers per Q-row. grid.y 32->16,
//    launch_bounds (256,2): 512 blocks = 2/CU resident.
//    Per chunk: [QK a | stage nxt + prefetch mc+2 | SM a | PV a |
//                QK b | SM b | PV b | barrier].
//    T12 in-register P reshape (validated R7) unchanged.
__global__ __launch_bounds__(256, 2) void attn_mfma(
    const ushort* __restrict__ qB, const ushort* __restrict__ kB,
    const ushort* __restrict__ vT, ushort* __restrict__ aH,
    ushort* __restrict__ aL) {
  __shared__ ushort sKa[2][8][264];
  __shared__ ushort sVa[2][8][264];
  int t = threadIdx.x;
  int lane = t & 63, w = t >> 6;
  int l31 = lane & 31, half = lane >> 5;
  int bh = blockIdx.x;
  int b = bh >> 3, h = bh & 7;
  int q0 = blockIdx.y * 256;

  const ushort* qrow = qB + ((size_t)bh * NN + q0 + w * 32 + l31) * 32;
  short8 bqa0 = *(const short8*)(qrow + half * 8);
  short8 bqa1 = *(const short8*)(qrow + 16 + half * 8);
  const ushort* qrow2 = qrow + 128 * 32;
  short8 bqb0 = *(const short8*)(qrow2 + half * 8);
  short8 bqb1 = *(const short8*)(qrow2 + 16 + half * 8);

  const ushort* kbase = kB + (size_t)bh * MM * 32;
  const ushort* vbase = vT + (size_t)bh * 32 * MM;
  int krow = t >> 2, kq = (t & 3) * 8;
  int vd = t >> 3, vmo = (t & 7) * 8;
  int kreg_idx = (krow >> 5) * 4 + (kq >> 4) * 2 + ((kq >> 3) & 1);
  int klane = (krow & 31) * 8;
  int vreg_idx = (vmo >> 4) * 2 + ((vmo >> 3) & 1);
  int vlane = vd * 8;

  short8 kr[2], vr[2];
  kr[0] = *(const short8*)&kbase[(size_t)krow * 32 + kq];
  vr[0] = *(const short8*)&vbase[(size_t)vd * MM + vmo];
  kr[1] = *(const short8*)&kbase[(size_t)(64 + krow) * 32 + kq];
  vr[1] = *(const short8*)&vbase[(size_t)vd * MM + 64 + vmo];
  *(short8*)&sKa[0][kreg_idx][klane] = kr[0];
  *(short8*)&sVa[0][vreg_idx][vlane] = vr[0];

  f32x16 oa, ob_;
#pragma unroll
  for (int i = 0; i < 16; ++i) { oa[i] = 0.f; ob_[i] = 0.f; }
  float psa = 0.f, psb = 0.f;
  __syncthreads();

  // One Q-set: QK^T, softmax (cvt_pk+permlane B-frags), PV.
  auto doset = [&](short8 q0f, short8 q1f, f32x16& o, float& psum, int cur) {
    f32x16 st[2];
    __builtin_amdgcn_s_setprio(1);
#pragma unroll
    for (int tt = 0; tt < 2; ++tt) {
      short8 a0 = *(const short8*)&sKa[cur][tt * 4 + 0 + half][l31 * 8];
      short8 a1 = *(const short8*)&sKa[cur][tt * 4 + 2 + half][l31 * 8];
      f32x16 z;
#pragma unroll
      for (int i = 0; i < 16; ++i) z[i] = 0.f;
      z = __builtin_amdgcn_mfma_f32_32x32x16_bf16(a0, q0f, z, 0, 0, 0);
      z = __builtin_amdgcn_mfma_f32_32x32x16_bf16(a1, q1f, z, 0, 0, 0);
      st[tt] = z;
    }
    __builtin_amdgcn_s_setprio(0);

    short8 bp[4];
#pragma unroll
    for (int tt = 0; tt < 2; ++tt) {
      float e[16];
#pragma unroll
      for (int i = 0; i < 16; ++i) e[i] = EXP2F(st[tt][i]);
#pragma unroll
      for (int i = 0; i < 16; i += 4)
        psum += (e[i] + e[i + 1]) + (e[i + 2] + e[i + 3]);
      unsigned pk[8];
#pragma unroll
      for (int j = 0; j < 8; ++j)
        asm("v_cvt_pk_bf16_f32 %0, %1, %2"
            : "=v"(pk[j]) : "v"(e[2 * j]), "v"(e[2 * j + 1]));
#pragma unroll
      for (int kbl = 0; kbl < 2; ++kbl) {
        unsigned w0 = pk[4 * kbl + 0], w2 = pk[4 * kbl + 2];
        unsigned w1 = pk[4 * kbl + 1], w3 = pk[4 * kbl + 3];
        asm("v_permlane32_swap_b32 %0, %1" : "+v"(w0), "+v"(w2));
        asm("v_permlane32_swap_b32 %0, %1" : "+v"(w1), "+v"(w3));
        uint32x4 wbits = {w0, w1, w2, w3};
        bp[2 * tt + kbl] = __builtin_bit_cast(short8, wbits);
      }
    }

    __builtin_amdgcn_s_setprio(1);
#pragma unroll
    for (int kb = 0; kb < 4; ++kb) {
      short8 av = *(const short8*)&sVa[cur][kb * 2 + half][l31 * 8];
      o = __builtin_amdgcn_mfma_f32_32x32x16_bf16(av, bp[kb], o, 0, 0, 0);
    }
    __builtin_amdgcn_s_setprio(0);
  };

#pragma unroll 2
  for (int mc = 0; mc < 16; ++mc) {
    int cur = mc & 1, nxt = cur ^ 1;

    doset(bqa0, bqa1, oa, psa, cur);

    // Store chunk mc+1 (loaded last iter -> vmcnt-free) into buffer nxt;
    // issue loads for chunk mc+2 into the set just freed. Overlaps set b.
    if (mc < 15) {
      *(short8*)&sKa[nxt][kreg_idx][klane] = kr[nxt];
      *(short8*)&sVa[nxt][vreg_idx][vlane] = vr[nxt];
    }
    if (mc < 14) {
      int m2 = (mc + 2) * 64;
      kr[cur] = *(const short8*)&kbase[(size_t)(m2 + krow) * 32 + kq];
      vr[cur] = *(const short8*)&vbase[(size_t)vd * MM + m2 + vmo];
    }

    doset(bqb0, bqb1, ob_, psb, cur);

    __syncthreads();
  }

  {
    float denom = psa + __shfl_xor(psa, 32);
    float inv = 1.f / denom;
    size_t rbase = ((size_t)b * NN + q0 + w * 32 + l31) * 256 + h * 32;
#pragma unroll
    for (int rg = 0; rg < 4; ++rg) {
#pragma unroll
      for (int j = 0; j < 4; ++j) {
        float v = oa[rg * 4 + j] * inv;
        ushort hi = f2bf(v);
        ushort lo = f2bf(v - bf2f(hi));
        int d = rg * 8 + half * 4 + j;
        aH[rbase + d] = hi;
        aL[rbase + d] = lo;
      }
    }
  }
  {
    float denom = psb + __shfl_xor(psb, 32);
    float inv = 1.f / denom;
    size_t rbase = ((size_t)b * NN + q0 + 128 + w * 32 + l31) * 256 + h * 32;
#pragma unroll
    for (int rg = 0; rg < 4; ++rg) {
#pragma unroll
      for (int j = 0; j < 4; ++j) {
        float v = ob_[rg * 4 + j] * inv;
        ushort hi = f2bf(v);
        ushort lo = f2bf(v - bf2f(hi));
        int d = rg * 8 + half * 4 + j;
        aH[rbase + d] = hi;
        aL[rbase + d] = lo;
      }
    }
  }
}

// ---------------------------------------------------------------------------
// 4) proj GEMM, hi/lo split on A and W, 64x64 tiles, double-buffered
//    single-barrier, depth-2 register pipeline. (unchanged)
__global__ __launch_bounds__(256) void gemm_proj(
    const ushort* __restrict__ A, const ushort* __restrict__ A2,
    const ushort* __restrict__ Whi, const ushort* __restrict__ Wlo,
    const float* __restrict__ bias, float* __restrict__ out) {
  __shared__ ushort smem[2][4 * 64 * 40];
  constexpr int OA = 0, OA2 = 64 * 40, OW = 2 * 64 * 40, OW2 = 3 * 64 * 40;
  int bid = blockIdx.x;
  int r0 = (bid >> 2) * 64, c0 = (bid & 3) * 64;

  int t = threadIdx.x;
  int lane = t & 63, w = t >> 6;
  int l31 = lane & 31, half = lane >> 5;
  int wr = w >> 1, wc = w & 1;
  int rowA = t >> 2, kq = (t & 3) * 8;

  f32x16 acc;
#pragma unroll
  for (int i = 0; i < 16; ++i) acc[i] = 0.f;

  short8 ra[2], ra2[2], rwh[2], rwl[2];
  auto prefetch = [&](int kc, int s) {
    ra[s]  = *(const short8*)&A[(size_t)(r0 + rowA) * 256 + kc + kq];
    ra2[s] = *(const short8*)&A2[(size_t)(r0 + rowA) * 256 + kc + kq];
    rwh[s] = *(const short8*)&Whi[(size_t)(c0 + rowA) * 256 + kc + kq];
    rwl[s] = *(const short8*)&Wlo[(size_t)(c0 + rowA) * 256 + kc + kq];
  };
  auto store = [&](ushort* buf, int s) {
    *(short8*)&buf[OA + rowA * 40 + kq] = ra[s];
    *(short8*)&buf[OA2 + rowA * 40 + kq] = ra2[s];
    *(short8*)&buf[OW + rowA * 40 + kq] = rwh[s];
    *(short8*)&buf[OW2 + rowA * 40 + kq] = rwl[s];
  };

  prefetch(0, 0);
  store(smem[0], 0);
  prefetch(32, 1);
  __syncthreads();
#pragma unroll
  for (int i = 0; i < 8; ++i) {
    ushort* cur = smem[i & 1];
    ushort* nxt = smem[(i & 1) ^ 1];
    if (i < 7) store(nxt, (i + 1) & 1);
    if (i < 6) prefetch((i + 2) * 32, i & 1);
#pragma unroll
    for (int ks = 0; ks < 2; ++ks) {
      int ro = (wr * 32 + l31) * 40 + ks * 16 + half * 8;
      int co = (wc * 32 + l31) * 40 + ks * 16 + half * 8;
      short8 af = *(const short8*)&cur[OA + ro];
      short8 af2 = *(const short8*)&cur[OA2 + ro];
      short8 wf = *(const short8*)&cur[OW + co];
      short8 wf2 = *(const short8*)&cur[OW2 + co];
      acc = __builtin_amdgcn_mfma_f32_32x32x16_bf16(af, wf, acc, 0, 0, 0);
      acc = __builtin_amdgcn_mfma_f32_32x32x16_bf16(af2, wf, acc, 0, 0, 0);
      acc = __builtin_amdgcn_mfma_f32_32x32x16_bf16(af, wf2, acc, 0, 0, 0);
    }
    __syncthreads();
  }

#pragma unroll
  for (int i = 0; i < 16; ++i) {
    int rl = (i & 3) + 8 * (i >> 2) + 4 * half;
    int r = r0 + wr * 32 + rl;
    int c = c0 + wc * 32 + l31;
    out[(size_t)r * 256 + c] = acc[i] + bias[c];
  }
}

// ---------------------------------------------------------------------------
extern "C" void kernel_launch(void* const* d_in, const int* in_sizes, int n_in,
                              void* d_out, int out_size, void* d_ws, size_t ws_size,
                              hipStream_t stream) {
  const float* x      = (const float*)d_in[0];
  const float* dw_w   = (const float*)d_in[1];
  const float* dw_b   = (const float*)d_in[2];
  const float* pw_w   = (const float*)d_in[3];
  const float* pw_b   = (const float*)d_in[4];
  const float* sr_w   = (const float*)d_in[5];
  const float* ln_g   = (const float*)d_in[6];
  const float* ln_b   = (const float*)d_in[7];
  const float* kv_w   = (const float*)d_in[8];
  const float* kv_b   = (const float*)d_in[9];
  const float* proj_w = (const float*)d_in[10];
  const float* proj_b = (const float*)d_in[11];
  float* out = (float*)d_out;

  char* ws = (char*)d_ws;
  ushort* q1b = (ushort*)(ws);                  // 16384x256 bf16  (8 MB)
  ushort* xsr = (ushort*)(ws + (8u << 20));     // 4096x256        (2 MB)
  ushort* qB  = (ushort*)(ws + (16u << 20));    // 32x4096x32      (8 MB)
  ushort* kBp = (ushort*)(ws + (24u << 20));    // 32x1024x32      (2 MB)
  ushort* vTp = (ushort*)(ws + (26u << 20));    // 32x32x1024      (2 MB)
  ushort* aH  = (ushort*)(ws + (28u << 20));    // 16384x256       (8 MB)
  ushort* aL  = (ushort*)(ws + (36u << 20));    // 16384x256       (8 MB)
  ushort* pwB = (ushort*)(ws + (44u << 20));                 // 128 KB
  ushort* kvB = (ushort*)(ws + (44u << 20) + (512u << 10));  // 256 KB
  ushort* pjH = (ushort*)(ws + (45u << 20));                 // 128 KB
  ushort* pjL = (ushort*)(ws + (45u << 20) + (512u << 10));  // 128 KB

  pre_fused<<<dim3(1792), 256, 0, stream>>>(x, dw_w, dw_b, sr_w, ln_g, ln_b,
                                            pw_w, kv_w, proj_w,
                                            q1b, xsr, pwB, kvB, pjH, pjL);
  gemm_qkv<<<dim3(1536), 256, 0, stream>>>(q1b, xsr, pwB, pw_b, kvB, kv_b,
                                           qB, kBp, vTp);
  attn_mfma<<<dim3(32, 16), 256, 0, stream>>>(qB, kBp, vTp, aH, aL);
  gemm_proj<<<dim3(1024), 256, 0, stream>>>(aH, aL, pjH, pjL, proj_b, out);
}